// Round 7
// baseline (131.738 us; speedup 1.0000x reference)
//
#include <hip/hip_runtime.h>

// Round 6: 3-dispatch pipeline (cvt fused away), occupancy fixes for GEMMs.
// qkv_fused: reads x/w_qkv fp32, converts inline during LDS staging.
//   128x64 tile, grid(12,64)=768 blocks (3/CU). Epilogue -> bf16
//   Q(pre-scaled SCALE*log2e)/K [bh][tok][d], V [bh][d][tok].
// attn_tile: R5 winner, unchanged. 64q x 128kv, k-split across waves,
//   sigma-permuted K staging, register-local P, double-buffered LDS.
// out_fused: 64x64 tile, grid(4,128)=512 blocks (2/CU), w_out converted
//   inline, fp32 out.

#define SEQ 2048
#define BATCH 4
#define NHEADS 8
#define HDIM 32
#define DIMC 256
#define SCALE_LOG2E 0.09016844005556021f  // (1/16)*log2(e)

typedef __attribute__((ext_vector_type(8))) short short8;
typedef __attribute__((ext_vector_type(4))) float f32x4;

union BF8 { unsigned u[4]; short8 s8; };

__device__ __forceinline__ unsigned pk2bf(float a, float b) {
    union { float f; unsigned u; } ua, ub;
    ua.f = a; ub.f = b;
    return __builtin_amdgcn_perm(ub.u + 0x8000u, ua.u + 0x8000u, 0x07060302u);
}
__device__ __forceinline__ short f2bf(float a) {
    union { float f; unsigned u; } x; x.f = a;
    return (short)((x.u + 0x8000u) >> 16);
}

// ---------------------------------------------------------------------------
// QKV GEMM, fused fp32->bf16 staging. C[8192][768] = x.w^T + b.
// 128m x 64n tile, BK=64, 4 K-iters. Waves 2x2: wave = 64m x 32n (4x2 acc).
// ---------------------------------------------------------------------------
__global__ __launch_bounds__(256) void qkv_fused(const float* __restrict__ X,
                                                 const float* __restrict__ W,
                                                 const float* __restrict__ bias,
                                                 short* __restrict__ Q,
                                                 short* __restrict__ Kd,
                                                 short* __restrict__ V) {
    __shared__ __align__(16) union SM {
        struct { short A[128][72]; short B[64][72]; } ab;   // 27648 B
        short CQ[128][72];                                  // Q/K epilogue
        short CV[64][136];                                  // V-transpose epilogue
    } sm;

    const int m0 = blockIdx.y * 128, bx = blockIdx.x;
    const int n0 = bx * 64;
    const int tid = threadIdx.x;
    const int w = tid >> 6, lane = tid & 63;
    const int m = lane & 15, g = lane >> 4;
    const int wr = w >> 1, wc = w & 1;

    // staging maps
    const int arow = tid >> 1, acol = (tid & 1) * 32;   // X: 128 rows x 64 k
    const int brow = tid >> 2, bcol = (tid & 3) * 16;   // W: 64 rows x 64 k

    f32x4 acc[4][2] = {};

    for (int kt = 0; kt < DIMC; kt += 64) {
        const float* xp = &X[(size_t)(m0 + arow) * DIMC + kt + acol];
        const float* wp = &W[(size_t)(n0 + brow) * DIMC + kt + bcol];
        float4 xv[8], wv[4];
#pragma unroll
        for (int i = 0; i < 8; i++) xv[i] = *(const float4*)(xp + i * 4);
#pragma unroll
        for (int i = 0; i < 4; i++) wv[i] = *(const float4*)(wp + i * 4);
        __syncthreads();
#pragma unroll
        for (int i = 0; i < 4; i++) {
            BF8 c;
            c.u[0] = pk2bf(xv[i * 2].x, xv[i * 2].y);
            c.u[1] = pk2bf(xv[i * 2].z, xv[i * 2].w);
            c.u[2] = pk2bf(xv[i * 2 + 1].x, xv[i * 2 + 1].y);
            c.u[3] = pk2bf(xv[i * 2 + 1].z, xv[i * 2 + 1].w);
            *(short8*)&sm.ab.A[arow][acol + i * 8] = c.s8;
        }
#pragma unroll
        for (int i = 0; i < 2; i++) {
            BF8 c;
            c.u[0] = pk2bf(wv[i * 2].x, wv[i * 2].y);
            c.u[1] = pk2bf(wv[i * 2].z, wv[i * 2].w);
            c.u[2] = pk2bf(wv[i * 2 + 1].x, wv[i * 2 + 1].y);
            c.u[3] = pk2bf(wv[i * 2 + 1].z, wv[i * 2 + 1].w);
            *(short8*)&sm.ab.B[brow][bcol + i * 8] = c.s8;
        }
        __syncthreads();
#pragma unroll
        for (int kk = 0; kk < 2; kk++) {
            short8 af[4], bf[2];
#pragma unroll
            for (int mt = 0; mt < 4; mt++)
                af[mt] = *(const short8*)&sm.ab.A[wr * 64 + mt * 16 + m][kk * 32 + g * 8];
#pragma unroll
            for (int nt = 0; nt < 2; nt++)
                bf[nt] = *(const short8*)&sm.ab.B[wc * 32 + nt * 16 + m][kk * 32 + g * 8];
#pragma unroll
            for (int mt = 0; mt < 4; mt++)
#pragma unroll
                for (int nt = 0; nt < 2; nt++)
                    acc[mt][nt] = __builtin_amdgcn_mfma_f32_16x16x32_bf16(af[mt], bf[nt], acc[mt][nt], 0, 0, 0);
        }
    }

    const int which = bx >> 2;            // 0=Q 1=K 2=V
    const int h0 = (bx & 3) * 2;          // 2 heads per 64-col tile
    const int bidx = blockIdx.y >> 4;
    const int ntok0 = (blockIdx.y & 15) * 128;
    float bv[2];
#pragma unroll
    for (int nt = 0; nt < 2; nt++) bv[nt] = bias[n0 + wc * 32 + nt * 16 + m];

    __syncthreads();
    if (which != 2) {
        const float qs = (which == 0) ? SCALE_LOG2E : 1.0f;
#pragma unroll
        for (int mt = 0; mt < 4; mt++)
#pragma unroll
            for (int nt = 0; nt < 2; nt++)
#pragma unroll
                for (int r = 0; r < 4; r++)
                    sm.CQ[wr * 64 + mt * 16 + g * 4 + r][wc * 32 + nt * 16 + m] =
                        f2bf((acc[mt][nt][r] + bv[nt]) * qs);
        __syncthreads();
        short* dst = (which == 0) ? Q : Kd;
        const int tok = tid >> 1, d0 = (tid & 1) * 16;
#pragma unroll
        for (int hh = 0; hh < 2; hh++) {
            size_t o = ((size_t)((bidx * NHEADS + h0 + hh) * SEQ) + ntok0 + tok) * HDIM + d0;
            *(short8*)&dst[o] = *(const short8*)&sm.CQ[tok][hh * 32 + d0];
            *(short8*)&dst[o + 8] = *(const short8*)&sm.CQ[tok][hh * 32 + d0 + 8];
        }
    } else {
        // transposed staging: CV[col][tok]
#pragma unroll
        for (int mt = 0; mt < 4; mt++)
#pragma unroll
            for (int nt = 0; nt < 2; nt++) {
                uint2 p;
                p.x = pk2bf(acc[mt][nt][0] + bv[nt], acc[mt][nt][1] + bv[nt]);
                p.y = pk2bf(acc[mt][nt][2] + bv[nt], acc[mt][nt][3] + bv[nt]);
                *(uint2*)&sm.CV[wc * 32 + nt * 16 + m][wr * 64 + mt * 16 + g * 4] = p;
            }
        __syncthreads();
        const int col = tid >> 2, t0 = (tid & 3) * 32;
        const int hh = col >> 5, d = col & 31;
        size_t o = ((size_t)((bidx * NHEADS + h0 + hh) * HDIM) + d) * SEQ + ntok0 + t0;
#pragma unroll
        for (int c2 = 0; c2 < 4; c2++)
            *(short8*)&V[o + c2 * 8] = *(const short8*)&sm.CV[col][t0 + c2 * 8];
    }
}

// ---------------------------------------------------------------------------
// Attention (R5, unchanged): 64 q-rows/block, KV tile 128, k split across
// 4 waves. Double-buffered LDS; sigma-permuted K; register-local P.
// ---------------------------------------------------------------------------
__global__ __launch_bounds__(256) void attn_tile(const short* __restrict__ Q,
                                                 const short* __restrict__ K,
                                                 const short* __restrict__ V,  // [bh][d][tok]
                                                 short* __restrict__ Zb) {
    __shared__ __align__(16) union SM {
        struct { short Ks[2][128][40]; short Vs[2][32][136]; } kv;   // 37888 B
        struct { float O[4][64][36]; float L[4][64]; } ep;           // 37888 B
    } sm;

    const int bh = blockIdx.y;
    const int b = bh >> 3, h = bh & 7;
    const int q0 = blockIdx.x * 64;
    const short* qb = Q + (size_t)bh * SEQ * HDIM;
    const short* kb = K + (size_t)bh * SEQ * HDIM;
    const short* vb = V + (size_t)bh * HDIM * SEQ;
    const int tid = threadIdx.x;
    const int w = tid >> 6, lane = tid & 63;
    const int m = lane & 15, g = lane >> 4;

    short8 qfr[4];
#pragma unroll
    for (int qt = 0; qt < 4; qt++)
        qfr[qt] = *(const short8*)(qb + (size_t)(q0 + qt * 16 + m) * HDIM + g * 8);

    const int krow = tid >> 1, kcol = (tid & 1) * 16;
    const int rl = krow & 31;
    const int lrow = (krow & ~31) | (((rl >> 2) & 1) << 4) | ((rl >> 3) << 2) | (rl & 3);
    const int vrow = tid >> 3, vcol = (tid & 7) * 16;

    f32x4 o[4][2] = {};
    f32x4 ol[4] = {};
    const short8 ones = {0x3F80, 0x3F80, 0x3F80, 0x3F80, 0x3F80, 0x3F80, 0x3F80, 0x3F80};

    short8 k0a = *(const short8*)(kb + (size_t)krow * HDIM + kcol);
    short8 k0b = *(const short8*)(kb + (size_t)krow * HDIM + kcol + 8);
    short8 v0a = *(const short8*)(vb + (size_t)vrow * SEQ + vcol);
    short8 v0b = *(const short8*)(vb + (size_t)vrow * SEQ + vcol + 8);
    *(short8*)&sm.kv.Ks[0][lrow][kcol] = k0a;
    *(short8*)&sm.kv.Ks[0][lrow][kcol + 8] = k0b;
    *(short8*)&sm.kv.Vs[0][vrow][vcol] = v0a;
    *(short8*)&sm.kv.Vs[0][vrow][vcol + 8] = v0b;
    __syncthreads();

    for (int it = 0; it < SEQ / 128; ++it) {
        const int buf = it & 1;
        if (it < SEQ / 128 - 1) {
            const int kn = (it + 1) * 128;
            k0a = *(const short8*)(kb + (size_t)(kn + krow) * HDIM + kcol);
            k0b = *(const short8*)(kb + (size_t)(kn + krow) * HDIM + kcol + 8);
            v0a = *(const short8*)(vb + (size_t)vrow * SEQ + kn + vcol);
            v0b = *(const short8*)(vb + (size_t)vrow * SEQ + kn + vcol + 8);
        }

        short8 kf0 = *(const short8*)&sm.kv.Ks[buf][w * 32 + m][g * 8];
        short8 kf1 = *(const short8*)&sm.kv.Ks[buf][w * 32 + 16 + m][g * 8];
        short8 vf0 = *(const short8*)&sm.kv.Vs[buf][m][w * 32 + g * 8];
        short8 vf1 = *(const short8*)&sm.kv.Vs[buf][16 + m][w * 32 + g * 8];

#pragma unroll
        for (int qt = 0; qt < 4; qt++) {
            f32x4 z4 = {0.f, 0.f, 0.f, 0.f};
            f32x4 st0 = __builtin_amdgcn_mfma_f32_16x16x32_bf16(kf0, qfr[qt], z4, 0, 0, 0);
            f32x4 st1 = __builtin_amdgcn_mfma_f32_16x16x32_bf16(kf1, qfr[qt], z4, 0, 0, 0);
            BF8 a;
            a.u[0] = pk2bf(__builtin_amdgcn_exp2f(st0[0]), __builtin_amdgcn_exp2f(st0[1]));
            a.u[1] = pk2bf(__builtin_amdgcn_exp2f(st0[2]), __builtin_amdgcn_exp2f(st0[3]));
            a.u[2] = pk2bf(__builtin_amdgcn_exp2f(st1[0]), __builtin_amdgcn_exp2f(st1[1]));
            a.u[3] = pk2bf(__builtin_amdgcn_exp2f(st1[2]), __builtin_amdgcn_exp2f(st1[3]));
            o[qt][0] = __builtin_amdgcn_mfma_f32_16x16x32_bf16(a.s8, vf0, o[qt][0], 0, 0, 0);
            o[qt][1] = __builtin_amdgcn_mfma_f32_16x16x32_bf16(a.s8, vf1, o[qt][1], 0, 0, 0);
            ol[qt] = __builtin_amdgcn_mfma_f32_16x16x32_bf16(a.s8, ones, ol[qt], 0, 0, 0);
        }

        if (it < SEQ / 128 - 1) {
            const int nb = buf ^ 1;
            *(short8*)&sm.kv.Ks[nb][lrow][kcol] = k0a;
            *(short8*)&sm.kv.Ks[nb][lrow][kcol + 8] = k0b;
            *(short8*)&sm.kv.Vs[nb][vrow][vcol] = v0a;
            *(short8*)&sm.kv.Vs[nb][vrow][vcol + 8] = v0b;
        }
        __syncthreads();
    }

#pragma unroll
    for (int qt = 0; qt < 4; qt++) {
#pragma unroll
        for (int dh = 0; dh < 2; dh++)
#pragma unroll
            for (int r = 0; r < 4; r++)
                sm.ep.O[w][qt * 16 + g * 4 + r][dh * 16 + m] = o[qt][dh][r];
        if (m == 0)
#pragma unroll
            for (int r = 0; r < 4; r++)
                sm.ep.L[w][qt * 16 + g * 4 + r] = ol[qt][r];
    }
    __syncthreads();

    const int ql = tid >> 2, d0 = (tid & 3) * 8;
    float lt = sm.ep.L[0][ql] + sm.ep.L[1][ql] + sm.ep.L[2][ql] + sm.ep.L[3][ql];
    float inv = __builtin_amdgcn_rcpf(lt);
    float sv[8];
#pragma unroll
    for (int j = 0; j < 8; j++)
        sv[j] = sm.ep.O[0][ql][d0 + j] + sm.ep.O[1][ql][d0 + j] +
                sm.ep.O[2][ql][d0 + j] + sm.ep.O[3][ql][d0 + j];
    BF8 pz;
#pragma unroll
    for (int j = 0; j < 4; j++)
        pz.u[j] = pk2bf(sv[2 * j] * inv, sv[2 * j + 1] * inv);
    *(short8*)&Zb[(size_t)(b * SEQ + q0 + ql) * DIMC + h * HDIM + d0] = pz.s8;
}

// ---------------------------------------------------------------------------
// Out GEMM, fused w conversion. out[8192][256] = Zb.w_out^T + b (fp32).
// 64x64 tile, grid(4,128)=512 blocks. Wave w = 16 rows x 64 cols.
// ---------------------------------------------------------------------------
__global__ __launch_bounds__(256) void out_fused(const short* __restrict__ A,
                                                 const float* __restrict__ W,
                                                 const float* __restrict__ bias,
                                                 float* __restrict__ C) {
    __shared__ __align__(16) short As[64][72];
    __shared__ __align__(16) short Bs[64][72];
    const int m0 = blockIdx.y * 64, n0 = blockIdx.x * 64;
    const int tid = threadIdx.x;
    const int w = tid >> 6, lane = tid & 63;
    const int m = lane & 15, g = lane >> 4;
    const int srow = tid >> 2, scol = (tid & 3) * 16;

    f32x4 acc[4] = {};

    for (int kt = 0; kt < DIMC; kt += 64) {
        short8 a0 = *(const short8*)&A[(size_t)(m0 + srow) * DIMC + kt + scol];
        short8 a1 = *(const short8*)&A[(size_t)(m0 + srow) * DIMC + kt + scol + 8];
        const float* wp = &W[(size_t)(n0 + srow) * DIMC + kt + scol];
        float4 wv[4];
#pragma unroll
        for (int i = 0; i < 4; i++) wv[i] = *(const float4*)(wp + i * 4);
        __syncthreads();
        *(short8*)&As[srow][scol] = a0;
        *(short8*)&As[srow][scol + 8] = a1;
#pragma unroll
        for (int i = 0; i < 2; i++) {
            BF8 c;
            c.u[0] = pk2bf(wv[i * 2].x, wv[i * 2].y);
            c.u[1] = pk2bf(wv[i * 2].z, wv[i * 2].w);
            c.u[2] = pk2bf(wv[i * 2 + 1].x, wv[i * 2 + 1].y);
            c.u[3] = pk2bf(wv[i * 2 + 1].z, wv[i * 2 + 1].w);
            *(short8*)&Bs[srow][scol + i * 8] = c.s8;
        }
        __syncthreads();
#pragma unroll
        for (int kk = 0; kk < 2; kk++) {
            short8 af = *(const short8*)&As[w * 16 + m][kk * 32 + g * 8];
#pragma unroll
            for (int nt = 0; nt < 4; nt++) {
                short8 bf = *(const short8*)&Bs[nt * 16 + m][kk * 32 + g * 8];
                acc[nt] = __builtin_amdgcn_mfma_f32_16x16x32_bf16(af, bf, acc[nt], 0, 0, 0);
            }
        }
    }

    float bv[4];
#pragma unroll
    for (int nt = 0; nt < 4; nt++) bv[nt] = bias[n0 + nt * 16 + m];
#pragma unroll
    for (int nt = 0; nt < 4; nt++)
#pragma unroll
        for (int r = 0; r < 4; r++)
            C[(size_t)(m0 + w * 16 + g * 4 + r) * DIMC + n0 + nt * 16 + m] = acc[nt][r] + bv[nt];
}

extern "C" void kernel_launch(void* const* d_in, const int* in_sizes, int n_in,
                              void* d_out, int out_size, void* d_ws, size_t ws_size,
                              hipStream_t stream) {
    const float* x     = (const float*)d_in[0];
    const float* w_qkv = (const float*)d_in[1];
    const float* b_qkv = (const float*)d_in[2];
    const float* w_out = (const float*)d_in[3];
    const float* b_out = (const float*)d_in[4];
    float* out = (float*)d_out;

    const size_t HSZ = (size_t)BATCH * NHEADS * SEQ * HDIM;  // 2M elems
    short* qw = (short*)d_ws;
    short* kw = qw + HSZ;
    short* vw = kw + HSZ;
    short* zb = vw + HSZ;

    qkv_fused<<<dim3(12, 64), 256, 0, stream>>>(x, w_qkv, b_qkv, qw, kw, vw);
    attn_tile<<<dim3(32, 32), 256, 0, stream>>>(qw, kw, vw, zb);
    out_fused<<<dim3(4, 128), 256, 0, stream>>>(zb, w_out, b_out, out);
}

// Round 8
// 119.954 us; speedup vs baseline: 1.0982x; 1.0982x over previous
//
#include <hip/hip_runtime.h>

// Round 7: R5 structure restored; GEMM K-loops software-pipelined
// (attn_tile's proven shape: stage->barrier->prefetch-next->compute),
// occupancy fixed: qkv 128x64 (768 blk, 3/CU), out 64x64 (512 blk, 2/CU).
// cvt_bf16 + attn_tile unchanged from R5.

#define SEQ 2048
#define BATCH 4
#define NHEADS 8
#define HDIM 32
#define DIMC 256
#define SCALE_LOG2E 0.09016844005556021f  // (1/16)*log2(e)

typedef __attribute__((ext_vector_type(8))) short short8;
typedef __attribute__((ext_vector_type(4))) float f32x4;

union BF8 { unsigned u[4]; short8 s8; };

__device__ __forceinline__ unsigned pk2bf(float a, float b) {
    union { float f; unsigned u; } ua, ub;
    ua.f = a; ub.f = b;
    return __builtin_amdgcn_perm(ub.u + 0x8000u, ua.u + 0x8000u, 0x07060302u);
}
__device__ __forceinline__ short f2bf(float a) {
    union { float f; unsigned u; } x; x.f = a;
    return (short)((x.u + 0x8000u) >> 16);
}

#define NX (BATCH * SEQ * DIMC)
#define NQW (3 * DIMC * DIMC)
#define NOW (DIMC * DIMC)

__global__ __launch_bounds__(256) void cvt_bf16(const float* __restrict__ x,
                                                const float* __restrict__ wq,
                                                const float* __restrict__ wo,
                                                short* __restrict__ xb,
                                                short* __restrict__ wqb,
                                                short* __restrict__ wob) {
    int i = (blockIdx.x * 256 + threadIdx.x) * 4;
    const float* src;
    short* dst;
    int off;
    if (i < NX) { src = x; dst = xb; off = i; }
    else if (i < NX + NQW) { src = wq; dst = wqb; off = i - NX; }
    else { src = wo; dst = wob; off = i - NX - NQW; }
    float4 v = *(const float4*)&src[off];
    uint2 p;
    p.x = pk2bf(v.x, v.y);
    p.y = pk2bf(v.z, v.w);
    *(uint2*)&dst[off] = p;
}

// ---------------------------------------------------------------------------
// QKV GEMM: C[8192][768] = Xb.Wb^T + b. 128m x 64n tile, grid(12,64)=768
// blocks (3/CU). BK=64, software-pipelined staging. Waves 2x2: wave = 64m x
// 32n, 16 MFMA per barrier-pair. Epilogue: coalesced bf16 scatter,
// Q(pre-scaled)/K -> [bh][tok][d], V -> [bh][d][tok].
// ---------------------------------------------------------------------------
__global__ __launch_bounds__(256) void qkv_mfma(const short* __restrict__ Xb,
                                                const short* __restrict__ Wb,
                                                const float* __restrict__ bias,
                                                short* __restrict__ Q,
                                                short* __restrict__ Kd,
                                                short* __restrict__ V) {
    __shared__ __align__(16) union SM {
        struct { short A[128][72]; short B[64][72]; } ab;   // 27648 B
        short CQ[128][72];
        short CV[64][136];
    } sm;

    const int m0 = blockIdx.y * 128, bx = blockIdx.x;
    const int n0 = bx * 64;
    const int tid = threadIdx.x;
    const int w = tid >> 6, lane = tid & 63;
    const int m = lane & 15, g = lane >> 4;
    const int wr = w >> 1, wc = w & 1;

    const int arow = tid >> 1, acol = (tid & 1) * 32;   // A: 128 x 64
    const int brow = tid >> 2, bcol = (tid & 3) * 16;   // B: 64 x 64

    f32x4 acc[4][2] = {};

    const short* ap = Xb + (size_t)(m0 + arow) * DIMC + acol;
    const short* bp = Wb + (size_t)(n0 + brow) * DIMC + bcol;

    short8 pa[4], pb[2];
#pragma unroll
    for (int i = 0; i < 4; i++) pa[i] = *(const short8*)(ap + i * 8);
#pragma unroll
    for (int i = 0; i < 2; i++) pb[i] = *(const short8*)(bp + i * 8);

    for (int kt = 0; kt < DIMC; kt += 64) {
        __syncthreads();
#pragma unroll
        for (int i = 0; i < 4; i++) *(short8*)&sm.ab.A[arow][acol + i * 8] = pa[i];
#pragma unroll
        for (int i = 0; i < 2; i++) *(short8*)&sm.ab.B[brow][bcol + i * 8] = pb[i];
        __syncthreads();
        if (kt + 64 < DIMC) {
#pragma unroll
            for (int i = 0; i < 4; i++) pa[i] = *(const short8*)(ap + kt + 64 + i * 8);
#pragma unroll
            for (int i = 0; i < 2; i++) pb[i] = *(const short8*)(bp + kt + 64 + i * 8);
        }
#pragma unroll
        for (int kk = 0; kk < 2; kk++) {
            short8 af[4], bf[2];
#pragma unroll
            for (int mt = 0; mt < 4; mt++)
                af[mt] = *(const short8*)&sm.ab.A[wr * 64 + mt * 16 + m][kk * 32 + g * 8];
#pragma unroll
            for (int nt = 0; nt < 2; nt++)
                bf[nt] = *(const short8*)&sm.ab.B[wc * 32 + nt * 16 + m][kk * 32 + g * 8];
#pragma unroll
            for (int mt = 0; mt < 4; mt++)
#pragma unroll
                for (int nt = 0; nt < 2; nt++)
                    acc[mt][nt] = __builtin_amdgcn_mfma_f32_16x16x32_bf16(af[mt], bf[nt], acc[mt][nt], 0, 0, 0);
        }
    }

    const int which = bx >> 2;            // 0=Q 1=K 2=V
    const int h0 = (bx & 3) * 2;          // 2 heads per 64-col tile
    const int bidx = blockIdx.y >> 4;
    const int ntok0 = (blockIdx.y & 15) * 128;
    float bv[2];
#pragma unroll
    for (int nt = 0; nt < 2; nt++) bv[nt] = bias[n0 + wc * 32 + nt * 16 + m];

    __syncthreads();
    if (which != 2) {
        const float qs = (which == 0) ? SCALE_LOG2E : 1.0f;
#pragma unroll
        for (int mt = 0; mt < 4; mt++)
#pragma unroll
            for (int nt = 0; nt < 2; nt++)
#pragma unroll
                for (int r = 0; r < 4; r++)
                    sm.CQ[wr * 64 + mt * 16 + g * 4 + r][wc * 32 + nt * 16 + m] =
                        f2bf((acc[mt][nt][r] + bv[nt]) * qs);
        __syncthreads();
        short* dst = (which == 0) ? Q : Kd;
        const int tok = tid >> 1, d0 = (tid & 1) * 16;
#pragma unroll
        for (int hh = 0; hh < 2; hh++) {
            size_t o = ((size_t)((bidx * NHEADS + h0 + hh) * SEQ) + ntok0 + tok) * HDIM + d0;
            *(short8*)&dst[o] = *(const short8*)&sm.CQ[tok][hh * 32 + d0];
            *(short8*)&dst[o + 8] = *(const short8*)&sm.CQ[tok][hh * 32 + d0 + 8];
        }
    } else {
#pragma unroll
        for (int mt = 0; mt < 4; mt++)
#pragma unroll
            for (int nt = 0; nt < 2; nt++) {
                uint2 p;
                p.x = pk2bf(acc[mt][nt][0] + bv[nt], acc[mt][nt][1] + bv[nt]);
                p.y = pk2bf(acc[mt][nt][2] + bv[nt], acc[mt][nt][3] + bv[nt]);
                *(uint2*)&sm.CV[wc * 32 + nt * 16 + m][wr * 64 + mt * 16 + g * 4] = p;
            }
        __syncthreads();
        const int col = tid >> 2, t0 = (tid & 3) * 32;
        const int hh = col >> 5, d = col & 31;
        size_t o = ((size_t)((bidx * NHEADS + h0 + hh) * HDIM) + d) * SEQ + ntok0 + t0;
#pragma unroll
        for (int c2 = 0; c2 < 4; c2++)
            *(short8*)&V[o + c2 * 8] = *(const short8*)&sm.CV[col][t0 + c2 * 8];
    }
}

// ---------------------------------------------------------------------------
// Attention (R5, unchanged): 64 q-rows/block, KV tile 128, k split across
// 4 waves. Double-buffered LDS; sigma-permuted K; register-local P.
// ---------------------------------------------------------------------------
__global__ __launch_bounds__(256) void attn_tile(const short* __restrict__ Q,
                                                 const short* __restrict__ K,
                                                 const short* __restrict__ V,  // [bh][d][tok]
                                                 short* __restrict__ Zb) {
    __shared__ __align__(16) union SM {
        struct { short Ks[2][128][40]; short Vs[2][32][136]; } kv;   // 37888 B
        struct { float O[4][64][36]; float L[4][64]; } ep;           // 37888 B
    } sm;

    const int bh = blockIdx.y;
    const int b = bh >> 3, h = bh & 7;
    const int q0 = blockIdx.x * 64;
    const short* qb = Q + (size_t)bh * SEQ * HDIM;
    const short* kb = K + (size_t)bh * SEQ * HDIM;
    const short* vb = V + (size_t)bh * HDIM * SEQ;
    const int tid = threadIdx.x;
    const int w = tid >> 6, lane = tid & 63;
    const int m = lane & 15, g = lane >> 4;

    short8 qfr[4];
#pragma unroll
    for (int qt = 0; qt < 4; qt++)
        qfr[qt] = *(const short8*)(qb + (size_t)(q0 + qt * 16 + m) * HDIM + g * 8);

    const int krow = tid >> 1, kcol = (tid & 1) * 16;
    const int rl = krow & 31;
    const int lrow = (krow & ~31) | (((rl >> 2) & 1) << 4) | ((rl >> 3) << 2) | (rl & 3);
    const int vrow = tid >> 3, vcol = (tid & 7) * 16;

    f32x4 o[4][2] = {};
    f32x4 ol[4] = {};
    const short8 ones = {0x3F80, 0x3F80, 0x3F80, 0x3F80, 0x3F80, 0x3F80, 0x3F80, 0x3F80};

    short8 k0a = *(const short8*)(kb + (size_t)krow * HDIM + kcol);
    short8 k0b = *(const short8*)(kb + (size_t)krow * HDIM + kcol + 8);
    short8 v0a = *(const short8*)(vb + (size_t)vrow * SEQ + vcol);
    short8 v0b = *(const short8*)(vb + (size_t)vrow * SEQ + vcol + 8);
    *(short8*)&sm.kv.Ks[0][lrow][kcol] = k0a;
    *(short8*)&sm.kv.Ks[0][lrow][kcol + 8] = k0b;
    *(short8*)&sm.kv.Vs[0][vrow][vcol] = v0a;
    *(short8*)&sm.kv.Vs[0][vrow][vcol + 8] = v0b;
    __syncthreads();

    for (int it = 0; it < SEQ / 128; ++it) {
        const int buf = it & 1;
        if (it < SEQ / 128 - 1) {
            const int kn = (it + 1) * 128;
            k0a = *(const short8*)(kb + (size_t)(kn + krow) * HDIM + kcol);
            k0b = *(const short8*)(kb + (size_t)(kn + krow) * HDIM + kcol + 8);
            v0a = *(const short8*)(vb + (size_t)vrow * SEQ + kn + vcol);
            v0b = *(const short8*)(vb + (size_t)vrow * SEQ + kn + vcol + 8);
        }

        short8 kf0 = *(const short8*)&sm.kv.Ks[buf][w * 32 + m][g * 8];
        short8 kf1 = *(const short8*)&sm.kv.Ks[buf][w * 32 + 16 + m][g * 8];
        short8 vf0 = *(const short8*)&sm.kv.Vs[buf][m][w * 32 + g * 8];
        short8 vf1 = *(const short8*)&sm.kv.Vs[buf][16 + m][w * 32 + g * 8];

#pragma unroll
        for (int qt = 0; qt < 4; qt++) {
            f32x4 z4 = {0.f, 0.f, 0.f, 0.f};
            f32x4 st0 = __builtin_amdgcn_mfma_f32_16x16x32_bf16(kf0, qfr[qt], z4, 0, 0, 0);
            f32x4 st1 = __builtin_amdgcn_mfma_f32_16x16x32_bf16(kf1, qfr[qt], z4, 0, 0, 0);
            BF8 a;
            a.u[0] = pk2bf(__builtin_amdgcn_exp2f(st0[0]), __builtin_amdgcn_exp2f(st0[1]));
            a.u[1] = pk2bf(__builtin_amdgcn_exp2f(st0[2]), __builtin_amdgcn_exp2f(st0[3]));
            a.u[2] = pk2bf(__builtin_amdgcn_exp2f(st1[0]), __builtin_amdgcn_exp2f(st1[1]));
            a.u[3] = pk2bf(__builtin_amdgcn_exp2f(st1[2]), __builtin_amdgcn_exp2f(st1[3]));
            o[qt][0] = __builtin_amdgcn_mfma_f32_16x16x32_bf16(a.s8, vf0, o[qt][0], 0, 0, 0);
            o[qt][1] = __builtin_amdgcn_mfma_f32_16x16x32_bf16(a.s8, vf1, o[qt][1], 0, 0, 0);
            ol[qt] = __builtin_amdgcn_mfma_f32_16x16x32_bf16(a.s8, ones, ol[qt], 0, 0, 0);
        }

        if (it < SEQ / 128 - 1) {
            const int nb = buf ^ 1;
            *(short8*)&sm.kv.Ks[nb][lrow][kcol] = k0a;
            *(short8*)&sm.kv.Ks[nb][lrow][kcol + 8] = k0b;
            *(short8*)&sm.kv.Vs[nb][vrow][vcol] = v0a;
            *(short8*)&sm.kv.Vs[nb][vrow][vcol + 8] = v0b;
        }
        __syncthreads();
    }

#pragma unroll
    for (int qt = 0; qt < 4; qt++) {
#pragma unroll
        for (int dh = 0; dh < 2; dh++)
#pragma unroll
            for (int r = 0; r < 4; r++)
                sm.ep.O[w][qt * 16 + g * 4 + r][dh * 16 + m] = o[qt][dh][r];
        if (m == 0)
#pragma unroll
            for (int r = 0; r < 4; r++)
                sm.ep.L[w][qt * 16 + g * 4 + r] = ol[qt][r];
    }
    __syncthreads();

    const int ql = tid >> 2, d0 = (tid & 3) * 8;
    float lt = sm.ep.L[0][ql] + sm.ep.L[1][ql] + sm.ep.L[2][ql] + sm.ep.L[3][ql];
    float inv = __builtin_amdgcn_rcpf(lt);
    float sv[8];
#pragma unroll
    for (int j = 0; j < 8; j++)
        sv[j] = sm.ep.O[0][ql][d0 + j] + sm.ep.O[1][ql][d0 + j] +
                sm.ep.O[2][ql][d0 + j] + sm.ep.O[3][ql][d0 + j];
    BF8 pz;
#pragma unroll
    for (int j = 0; j < 4; j++)
        pz.u[j] = pk2bf(sv[2 * j] * inv, sv[2 * j + 1] * inv);
    *(short8*)&Zb[(size_t)(b * SEQ + q0 + ql) * DIMC + h * HDIM + d0] = pz.s8;
}

// ---------------------------------------------------------------------------
// Out GEMM: out[8192][256] = Zb.Wob^T + b (fp32). 64x64 tile, grid(4,128)
// = 512 blocks (2/CU). Software-pipelined staging; 8 MFMA per barrier-pair.
// ---------------------------------------------------------------------------
__global__ __launch_bounds__(256) void out_mfma(const short* __restrict__ A,
                                                const short* __restrict__ Wb,
                                                const float* __restrict__ bias,
                                                float* __restrict__ C) {
    __shared__ __align__(16) short As[64][72];
    __shared__ __align__(16) short Bs[64][72];
    const int m0 = blockIdx.y * 64, n0 = blockIdx.x * 64;
    const int tid = threadIdx.x;
    const int w = tid >> 6, lane = tid & 63;
    const int m = lane & 15, g = lane >> 4;
    const int srow = tid >> 2, scol = (tid & 3) * 16;

    f32x4 acc[4] = {};

    const short* ap = A + (size_t)(m0 + srow) * DIMC + scol;
    const short* bp = Wb + (size_t)(n0 + srow) * DIMC + scol;

    short8 pa[2], pb[2];
#pragma unroll
    for (int i = 0; i < 2; i++) {
        pa[i] = *(const short8*)(ap + i * 8);
        pb[i] = *(const short8*)(bp + i * 8);
    }

    for (int kt = 0; kt < DIMC; kt += 64) {
        __syncthreads();
#pragma unroll
        for (int i = 0; i < 2; i++) {
            *(short8*)&As[srow][scol + i * 8] = pa[i];
            *(short8*)&Bs[srow][scol + i * 8] = pb[i];
        }
        __syncthreads();
        if (kt + 64 < DIMC) {
#pragma unroll
            for (int i = 0; i < 2; i++) {
                pa[i] = *(const short8*)(ap + kt + 64 + i * 8);
                pb[i] = *(const short8*)(bp + kt + 64 + i * 8);
            }
        }
#pragma unroll
        for (int kk = 0; kk < 2; kk++) {
            short8 af = *(const short8*)&As[w * 16 + m][kk * 32 + g * 8];
#pragma unroll
            for (int nt = 0; nt < 4; nt++) {
                short8 bf = *(const short8*)&Bs[nt * 16 + m][kk * 32 + g * 8];
                acc[nt] = __builtin_amdgcn_mfma_f32_16x16x32_bf16(af, bf, acc[nt], 0, 0, 0);
            }
        }
    }

    float bv[4];
#pragma unroll
    for (int nt = 0; nt < 4; nt++) bv[nt] = bias[n0 + nt * 16 + m];
#pragma unroll
    for (int nt = 0; nt < 4; nt++)
#pragma unroll
        for (int r = 0; r < 4; r++)
            C[(size_t)(m0 + w * 16 + g * 4 + r) * DIMC + n0 + nt * 16 + m] = acc[nt][r] + bv[nt];
}

extern "C" void kernel_launch(void* const* d_in, const int* in_sizes, int n_in,
                              void* d_out, int out_size, void* d_ws, size_t ws_size,
                              hipStream_t stream) {
    const float* x     = (const float*)d_in[0];
    const float* w_qkv = (const float*)d_in[1];
    const float* b_qkv = (const float*)d_in[2];
    const float* w_out = (const float*)d_in[3];
    const float* b_out = (const float*)d_in[4];
    float* out = (float*)d_out;

    const size_t HSZ = (size_t)BATCH * NHEADS * SEQ * HDIM;
    short* xb  = (short*)d_ws;
    short* wqb = xb + NX;
    short* wob = wqb + NQW;
    short* qw  = wob + NOW;
    short* kw  = qw + HSZ;
    short* vw  = kw + HSZ;
    short* zb  = vw + HSZ;

    cvt_bf16<<<(NX + NQW + NOW) / 1024, 256, 0, stream>>>(x, w_qkv, w_out, xb, wqb, wob);
    qkv_mfma<<<dim3(12, 64), 256, 0, stream>>>(xb, wqb, b_qkv, qw, kw, vw);
    attn_tile<<<dim3(32, 32), 256, 0, stream>>>(qw, kw, vw, zb);
    out_mfma<<<dim3(4, 128), 256, 0, stream>>>(zb, wob, b_out, out);
}

// Round 9
// 111.591 us; speedup vs baseline: 1.1805x; 1.0749x over previous
//
#include <hip/hip_runtime.h>

// Round 8: attention arithmetic-intensity doubling. 128 q-rows/block
// (8 q-frags/wave), KV tile 128, grid(16,32)=512 blocks. 40 MFMA per
// wave-iter vs 12, same LDS staging -> per-CU LDS traffic and KV L2
// re-reads halve. Two-phase epilogue. GEMMs/cvt = R7 (pipelined).

#define SEQ 2048
#define BATCH 4
#define NHEADS 8
#define HDIM 32
#define DIMC 256
#define SCALE_LOG2E 0.09016844005556021f  // (1/16)*log2(e)

typedef __attribute__((ext_vector_type(8))) short short8;
typedef __attribute__((ext_vector_type(4))) float f32x4;

union BF8 { unsigned u[4]; short8 s8; };

__device__ __forceinline__ unsigned pk2bf(float a, float b) {
    union { float f; unsigned u; } ua, ub;
    ua.f = a; ub.f = b;
    return __builtin_amdgcn_perm(ub.u + 0x8000u, ua.u + 0x8000u, 0x07060302u);
}
__device__ __forceinline__ short f2bf(float a) {
    union { float f; unsigned u; } x; x.f = a;
    return (short)((x.u + 0x8000u) >> 16);
}

#define NX (BATCH * SEQ * DIMC)
#define NQW (3 * DIMC * DIMC)
#define NOW (DIMC * DIMC)

__global__ __launch_bounds__(256) void cvt_bf16(const float* __restrict__ x,
                                                const float* __restrict__ wq,
                                                const float* __restrict__ wo,
                                                short* __restrict__ xb,
                                                short* __restrict__ wqb,
                                                short* __restrict__ wob) {
    int i = (blockIdx.x * 256 + threadIdx.x) * 4;
    const float* src;
    short* dst;
    int off;
    if (i < NX) { src = x; dst = xb; off = i; }
    else if (i < NX + NQW) { src = wq; dst = wqb; off = i - NX; }
    else { src = wo; dst = wob; off = i - NX - NQW; }
    float4 v = *(const float4*)&src[off];
    uint2 p;
    p.x = pk2bf(v.x, v.y);
    p.y = pk2bf(v.z, v.w);
    *(uint2*)&dst[off] = p;
}

// ---------------------------------------------------------------------------
// QKV GEMM (R7): 128x64 tile, 768 blocks, software-pipelined staging.
// ---------------------------------------------------------------------------
__global__ __launch_bounds__(256) void qkv_mfma(const short* __restrict__ Xb,
                                                const short* __restrict__ Wb,
                                                const float* __restrict__ bias,
                                                short* __restrict__ Q,
                                                short* __restrict__ Kd,
                                                short* __restrict__ V) {
    __shared__ __align__(16) union SM {
        struct { short A[128][72]; short B[64][72]; } ab;
        short CQ[128][72];
        short CV[64][136];
    } sm;

    const int m0 = blockIdx.y * 128, bx = blockIdx.x;
    const int n0 = bx * 64;
    const int tid = threadIdx.x;
    const int w = tid >> 6, lane = tid & 63;
    const int m = lane & 15, g = lane >> 4;
    const int wr = w >> 1, wc = w & 1;

    const int arow = tid >> 1, acol = (tid & 1) * 32;
    const int brow = tid >> 2, bcol = (tid & 3) * 16;

    f32x4 acc[4][2] = {};

    const short* ap = Xb + (size_t)(m0 + arow) * DIMC + acol;
    const short* bp = Wb + (size_t)(n0 + brow) * DIMC + bcol;

    short8 pa[4], pb[2];
#pragma unroll
    for (int i = 0; i < 4; i++) pa[i] = *(const short8*)(ap + i * 8);
#pragma unroll
    for (int i = 0; i < 2; i++) pb[i] = *(const short8*)(bp + i * 8);

    for (int kt = 0; kt < DIMC; kt += 64) {
        __syncthreads();
#pragma unroll
        for (int i = 0; i < 4; i++) *(short8*)&sm.ab.A[arow][acol + i * 8] = pa[i];
#pragma unroll
        for (int i = 0; i < 2; i++) *(short8*)&sm.ab.B[brow][bcol + i * 8] = pb[i];
        __syncthreads();
        if (kt + 64 < DIMC) {
#pragma unroll
            for (int i = 0; i < 4; i++) pa[i] = *(const short8*)(ap + kt + 64 + i * 8);
#pragma unroll
            for (int i = 0; i < 2; i++) pb[i] = *(const short8*)(bp + kt + 64 + i * 8);
        }
#pragma unroll
        for (int kk = 0; kk < 2; kk++) {
            short8 af[4], bf[2];
#pragma unroll
            for (int mt = 0; mt < 4; mt++)
                af[mt] = *(const short8*)&sm.ab.A[wr * 64 + mt * 16 + m][kk * 32 + g * 8];
#pragma unroll
            for (int nt = 0; nt < 2; nt++)
                bf[nt] = *(const short8*)&sm.ab.B[wc * 32 + nt * 16 + m][kk * 32 + g * 8];
#pragma unroll
            for (int mt = 0; mt < 4; mt++)
#pragma unroll
                for (int nt = 0; nt < 2; nt++)
                    acc[mt][nt] = __builtin_amdgcn_mfma_f32_16x16x32_bf16(af[mt], bf[nt], acc[mt][nt], 0, 0, 0);
        }
    }

    const int which = bx >> 2;
    const int h0 = (bx & 3) * 2;
    const int bidx = blockIdx.y >> 4;
    const int ntok0 = (blockIdx.y & 15) * 128;
    float bv[2];
#pragma unroll
    for (int nt = 0; nt < 2; nt++) bv[nt] = bias[n0 + wc * 32 + nt * 16 + m];

    __syncthreads();
    if (which != 2) {
        const float qs = (which == 0) ? SCALE_LOG2E : 1.0f;
#pragma unroll
        for (int mt = 0; mt < 4; mt++)
#pragma unroll
            for (int nt = 0; nt < 2; nt++)
#pragma unroll
                for (int r = 0; r < 4; r++)
                    sm.CQ[wr * 64 + mt * 16 + g * 4 + r][wc * 32 + nt * 16 + m] =
                        f2bf((acc[mt][nt][r] + bv[nt]) * qs);
        __syncthreads();
        short* dst = (which == 0) ? Q : Kd;
        const int tok = tid >> 1, d0 = (tid & 1) * 16;
#pragma unroll
        for (int hh = 0; hh < 2; hh++) {
            size_t o = ((size_t)((bidx * NHEADS + h0 + hh) * SEQ) + ntok0 + tok) * HDIM + d0;
            *(short8*)&dst[o] = *(const short8*)&sm.CQ[tok][hh * 32 + d0];
            *(short8*)&dst[o + 8] = *(const short8*)&sm.CQ[tok][hh * 32 + d0 + 8];
        }
    } else {
#pragma unroll
        for (int mt = 0; mt < 4; mt++)
#pragma unroll
            for (int nt = 0; nt < 2; nt++) {
                uint2 p;
                p.x = pk2bf(acc[mt][nt][0] + bv[nt], acc[mt][nt][1] + bv[nt]);
                p.y = pk2bf(acc[mt][nt][2] + bv[nt], acc[mt][nt][3] + bv[nt]);
                *(uint2*)&sm.CV[wc * 32 + nt * 16 + m][wr * 64 + mt * 16 + g * 4] = p;
            }
        __syncthreads();
        const int col = tid >> 2, t0 = (tid & 3) * 32;
        const int hh = col >> 5, d = col & 31;
        size_t o = ((size_t)((bidx * NHEADS + h0 + hh) * HDIM) + d) * SEQ + ntok0 + t0;
#pragma unroll
        for (int c2 = 0; c2 < 4; c2++)
            *(short8*)&V[o + c2 * 8] = *(const short8*)&sm.CV[col][t0 + c2 * 8];
    }
}

// ---------------------------------------------------------------------------
// Attention: 128 q-rows/block, KV tile 128, k split across 4 waves.
// Double-buffered LDS; sigma-permuted K; register-local P; 8 q-frags/wave;
// two-phase cross-wave epilogue. grid(16,32)=512 blocks.
// ---------------------------------------------------------------------------
__global__ __launch_bounds__(256, 2) void attn_tile(const short* __restrict__ Q,
                                                    const short* __restrict__ K,
                                                    const short* __restrict__ V,  // [bh][d][tok]
                                                    short* __restrict__ Zb) {
    __shared__ __align__(16) union SM {
        struct { short Ks[2][128][40]; short Vs[2][32][136]; } kv;   // 37888 B
        struct { float O[4][64][36]; float L[4][64]; } ep;           // 37888 B
    } sm;

    const int bh = blockIdx.y;
    const int b = bh >> 3, h = bh & 7;
    const int q0 = blockIdx.x * 128;
    const short* qb = Q + (size_t)bh * SEQ * HDIM;
    const short* kb = K + (size_t)bh * SEQ * HDIM;
    const short* vb = V + (size_t)bh * HDIM * SEQ;
    const int tid = threadIdx.x;
    const int w = tid >> 6, lane = tid & 63;
    const int m = lane & 15, g = lane >> 4;

    short8 qfr[8];
#pragma unroll
    for (int qt = 0; qt < 8; qt++)
        qfr[qt] = *(const short8*)(qb + (size_t)(q0 + qt * 16 + m) * HDIM + g * 8);

    const int krow = tid >> 1, kcol = (tid & 1) * 16;
    const int rl = krow & 31;
    const int lrow = (krow & ~31) | (((rl >> 2) & 1) << 4) | ((rl >> 3) << 2) | (rl & 3);
    const int vrow = tid >> 3, vcol = (tid & 7) * 16;

    f32x4 o[8][2] = {};
    f32x4 ol[8] = {};
    const short8 ones = {0x3F80, 0x3F80, 0x3F80, 0x3F80, 0x3F80, 0x3F80, 0x3F80, 0x3F80};

    short8 k0a = *(const short8*)(kb + (size_t)krow * HDIM + kcol);
    short8 k0b = *(const short8*)(kb + (size_t)krow * HDIM + kcol + 8);
    short8 v0a = *(const short8*)(vb + (size_t)vrow * SEQ + vcol);
    short8 v0b = *(const short8*)(vb + (size_t)vrow * SEQ + vcol + 8);
    *(short8*)&sm.kv.Ks[0][lrow][kcol] = k0a;
    *(short8*)&sm.kv.Ks[0][lrow][kcol + 8] = k0b;
    *(short8*)&sm.kv.Vs[0][vrow][vcol] = v0a;
    *(short8*)&sm.kv.Vs[0][vrow][vcol + 8] = v0b;
    __syncthreads();

    for (int it = 0; it < SEQ / 128; ++it) {
        const int buf = it & 1;
        if (it < SEQ / 128 - 1) {
            const int kn = (it + 1) * 128;
            k0a = *(const short8*)(kb + (size_t)(kn + krow) * HDIM + kcol);
            k0b = *(const short8*)(kb + (size_t)(kn + krow) * HDIM + kcol + 8);
            v0a = *(const short8*)(vb + (size_t)vrow * SEQ + kn + vcol);
            v0b = *(const short8*)(vb + (size_t)vrow * SEQ + kn + vcol + 8);
        }

        short8 kf0 = *(const short8*)&sm.kv.Ks[buf][w * 32 + m][g * 8];
        short8 kf1 = *(const short8*)&sm.kv.Ks[buf][w * 32 + 16 + m][g * 8];
        short8 vf0 = *(const short8*)&sm.kv.Vs[buf][m][w * 32 + g * 8];
        short8 vf1 = *(const short8*)&sm.kv.Vs[buf][16 + m][w * 32 + g * 8];

#pragma unroll
        for (int qt = 0; qt < 8; qt++) {
            f32x4 z4 = {0.f, 0.f, 0.f, 0.f};
            f32x4 st0 = __builtin_amdgcn_mfma_f32_16x16x32_bf16(kf0, qfr[qt], z4, 0, 0, 0);
            f32x4 st1 = __builtin_amdgcn_mfma_f32_16x16x32_bf16(kf1, qfr[qt], z4, 0, 0, 0);
            BF8 a;
            a.u[0] = pk2bf(__builtin_amdgcn_exp2f(st0[0]), __builtin_amdgcn_exp2f(st0[1]));
            a.u[1] = pk2bf(__builtin_amdgcn_exp2f(st0[2]), __builtin_amdgcn_exp2f(st0[3]));
            a.u[2] = pk2bf(__builtin_amdgcn_exp2f(st1[0]), __builtin_amdgcn_exp2f(st1[1]));
            a.u[3] = pk2bf(__builtin_amdgcn_exp2f(st1[2]), __builtin_amdgcn_exp2f(st1[3]));
            o[qt][0] = __builtin_amdgcn_mfma_f32_16x16x32_bf16(a.s8, vf0, o[qt][0], 0, 0, 0);
            o[qt][1] = __builtin_amdgcn_mfma_f32_16x16x32_bf16(a.s8, vf1, o[qt][1], 0, 0, 0);
            ol[qt] = __builtin_amdgcn_mfma_f32_16x16x32_bf16(a.s8, ones, ol[qt], 0, 0, 0);
        }

        if (it < SEQ / 128 - 1) {
            const int nb = buf ^ 1;
            *(short8*)&sm.kv.Ks[nb][lrow][kcol] = k0a;
            *(short8*)&sm.kv.Ks[nb][lrow][kcol + 8] = k0b;
            *(short8*)&sm.kv.Vs[nb][vrow][vcol] = v0a;
            *(short8*)&sm.kv.Vs[nb][vrow][vcol + 8] = v0b;
        }
        __syncthreads();
    }

    // Two-phase cross-wave reduction (64 q-rows per phase; LDS union reuse).
#pragma unroll
    for (int ph = 0; ph < 2; ph++) {
        if (ph) __syncthreads();
#pragma unroll
        for (int qt = 0; qt < 4; qt++) {
            const int qq = ph * 4 + qt;
#pragma unroll
            for (int dh = 0; dh < 2; dh++)
#pragma unroll
                for (int r = 0; r < 4; r++)
                    sm.ep.O[w][qt * 16 + g * 4 + r][dh * 16 + m] = o[qq][dh][r];
            if (m == 0)
#pragma unroll
                for (int r = 0; r < 4; r++)
                    sm.ep.L[w][qt * 16 + g * 4 + r] = ol[qq][r];
        }
        __syncthreads();

        const int ql = tid >> 2, d0 = (tid & 3) * 8;
        float lt = sm.ep.L[0][ql] + sm.ep.L[1][ql] + sm.ep.L[2][ql] + sm.ep.L[3][ql];
        float inv = __builtin_amdgcn_rcpf(lt);
        float sv[8];
#pragma unroll
        for (int j = 0; j < 8; j++)
            sv[j] = sm.ep.O[0][ql][d0 + j] + sm.ep.O[1][ql][d0 + j] +
                    sm.ep.O[2][ql][d0 + j] + sm.ep.O[3][ql][d0 + j];
        BF8 pz;
#pragma unroll
        for (int j = 0; j < 4; j++)
            pz.u[j] = pk2bf(sv[2 * j] * inv, sv[2 * j + 1] * inv);
        *(short8*)&Zb[(size_t)(b * SEQ + q0 + ph * 64 + ql) * DIMC + h * HDIM + d0] = pz.s8;
    }
}

// ---------------------------------------------------------------------------
// Out GEMM (R7): 64x64 tile, 512 blocks, software-pipelined staging.
// ---------------------------------------------------------------------------
__global__ __launch_bounds__(256) void out_mfma(const short* __restrict__ A,
                                                const short* __restrict__ Wb,
                                                const float* __restrict__ bias,
                                                float* __restrict__ C) {
    __shared__ __align__(16) short As[64][72];
    __shared__ __align__(16) short Bs[64][72];
    const int m0 = blockIdx.y * 64, n0 = blockIdx.x * 64;
    const int tid = threadIdx.x;
    const int w = tid >> 6, lane = tid & 63;
    const int m = lane & 15, g = lane >> 4;
    const int srow = tid >> 2, scol = (tid & 3) * 16;

    f32x4 acc[4] = {};

    const short* ap = A + (size_t)(m0 + srow) * DIMC + scol;
    const short* bp = Wb + (size_t)(n0 + srow) * DIMC + scol;

    short8 pa[2], pb[2];
#pragma unroll
    for (int i = 0; i < 2; i++) {
        pa[i] = *(const short8*)(ap + i * 8);
        pb[i] = *(const short8*)(bp + i * 8);
    }

    for (int kt = 0; kt < DIMC; kt += 64) {
        __syncthreads();
#pragma unroll
        for (int i = 0; i < 2; i++) {
            *(short8*)&As[srow][scol + i * 8] = pa[i];
            *(short8*)&Bs[srow][scol + i * 8] = pb[i];
        }
        __syncthreads();
        if (kt + 64 < DIMC) {
#pragma unroll
            for (int i = 0; i < 2; i++) {
                pa[i] = *(const short8*)(ap + kt + 64 + i * 8);
                pb[i] = *(const short8*)(bp + kt + 64 + i * 8);
            }
        }
#pragma unroll
        for (int kk = 0; kk < 2; kk++) {
            short8 af = *(const short8*)&As[w * 16 + m][kk * 32 + g * 8];
#pragma unroll
            for (int nt = 0; nt < 4; nt++) {
                short8 bf = *(const short8*)&Bs[nt * 16 + m][kk * 32 + g * 8];
                acc[nt] = __builtin_amdgcn_mfma_f32_16x16x32_bf16(af, bf, acc[nt], 0, 0, 0);
            }
        }
    }

    float bv[4];
#pragma unroll
    for (int nt = 0; nt < 4; nt++) bv[nt] = bias[n0 + nt * 16 + m];
#pragma unroll
    for (int nt = 0; nt < 4; nt++)
#pragma unroll
        for (int r = 0; r < 4; r++)
            C[(size_t)(m0 + w * 16 + g * 4 + r) * DIMC + n0 + nt * 16 + m] = acc[nt][r] + bv[nt];
}

extern "C" void kernel_launch(void* const* d_in, const int* in_sizes, int n_in,
                              void* d_out, int out_size, void* d_ws, size_t ws_size,
                              hipStream_t stream) {
    const float* x     = (const float*)d_in[0];
    const float* w_qkv = (const float*)d_in[1];
    const float* b_qkv = (const float*)d_in[2];
    const float* w_out = (const float*)d_in[3];
    const float* b_out = (const float*)d_in[4];
    float* out = (float*)d_out;

    const size_t HSZ = (size_t)BATCH * NHEADS * SEQ * HDIM;
    short* xb  = (short*)d_ws;
    short* wqb = xb + NX;
    short* wob = wqb + NQW;
    short* qw  = wob + NOW;
    short* kw  = qw + HSZ;
    short* vw  = kw + HSZ;
    short* zb  = vw + HSZ;

    cvt_bf16<<<(NX + NQW + NOW) / 1024, 256, 0, stream>>>(x, w_qkv, w_out, xb, wqb, wob);
    qkv_mfma<<<dim3(12, 64), 256, 0, stream>>>(xb, wqb, b_qkv, qw, kw, vw);
    attn_tile<<<dim3(16, 32), 256, 0, stream>>>(qw, kw, vw, zb);
    out_mfma<<<dim3(4, 128), 256, 0, stream>>>(zb, wob, b_out, out);
}